// Round 3
// baseline (142.020 us; speedup 1.0000x reference)
//
#include <hip/hip_runtime.h>
#include <math.h>

// img (8, 3, 1024, 2048) fp32 -> same-shape fp32 output.
#define Wd 2048
#define Hd 1024
#define BC 24
#define CH 32          // output rows per block
#define NT 512         // 8 waves; lane owns 4 consecutive cols; wave owns 256 cols
#define NW 8

__device__ __forceinline__ float masked_grad1(float g1, float g2, float g3) {
    const float HALF_T     = (float)(0.5 / 1023.0);
    const float GRD_BOTTOM = (float)(1.0 / 1023.0);
    const float GRD_UP     = (float)(4.0 / 1023.0);
    const float THIRD      = (float)(1.0 / 3.0);
    float m = (g1 + g2 + g3) * THIRD;
    float g = (g1 < m - HALF_T || g1 > m + HALF_T) ? 0.0f : g1;
    float ag = fabsf(g);
    if (ag < GRD_BOTTOM || ag > GRD_UP) g = 0.0f;
    return g;
}

__device__ __forceinline__ float4 f4s(float v) { return make_float4(v, v, v, v); }

__device__ __forceinline__ float4 shflup1(float4 v) {
    float4 r;
    r.x = __shfl_up(v.x, 1, 64); r.y = __shfl_up(v.y, 1, 64);
    r.z = __shfl_up(v.z, 1, 64); r.w = __shfl_up(v.w, 1, 64);
    return r;
}
__device__ __forceinline__ float4 shfldn1(float4 v) {
    float4 r;
    r.x = __shfl_down(v.x, 1, 64); r.y = __shfl_down(v.y, 1, 64);
    r.z = __shfl_down(v.z, 1, 64); r.w = __shfl_down(v.w, 1, 64);
    return r;
}

__global__ __launch_bounds__(NT, 4) void gradmap_shfl_kernel(
        const float* __restrict__ img, float* __restrict__ out) {
    const int plane = blockIdx.y;
    const int y0 = blockIdx.x * CH;
    const int tid = threadIdx.x;
    const int lane = tid & 63;
    const int wv = tid >> 6;
    const int c0 = tid << 2;
    const float* __restrict__ ip = img + (size_t)plane * Hd * Wd + c0;
    float* __restrict__ op = out + (size_t)plane * Hd * Wd + c0;

    // Tiny cross-wave edge buffers (double/quad-buffered by row parity).
    __shared__ float4 s_iL[4][NW], s_iR[4][NW];   // img row edges (ring of 4)
    __shared__ float  s_gL[2][NW], s_gR[2][NW];   // grad row edge scalars
    __shared__ float  s_vL[2][NW], s_vR[2][NW];   // vmax row edge scalars

    // img register ring: im0 = newest row L ... im6 = row L-6 (own 4 cols)
    float4 im0 = f4s(0.f), im1 = f4s(0.f), im2 = f4s(0.f), im3 = f4s(0.f),
           im4 = f4s(0.f), im5 = f4s(0.f), im6 = f4s(0.f);

    // ---- prime: rows y0-6 .. y0-1 (loads + edge publishes only) ----
    #pragma unroll
    for (int r = 0; r < 6; ++r) {
        int row = y0 - 6 + r;
        float4 v = f4s(0.f);
        if (row >= 0) v = *(const float4*)(ip + (size_t)row * Wd);
        im6 = im5; im5 = im4; im4 = im3; im3 = im2; im2 = im1; im1 = im0; im0 = v;
        if (lane == 0)  s_iL[row & 3][wv] = v;
        if (lane == 63) s_iR[row & 3][wv] = v;
    }
    float4 vpref = *(const float4*)(ip + (size_t)y0 * Wd);  // y0 < Hd always
    __syncthreads();

    float4 gprev  = f4s(0.f);
    float4 h0 = f4s(-INFINITY), h1 = f4s(-INFINITY);
    float4 vmprev = f4s(INFINITY);
    float4 n0 = f4s(INFINITY), n1 = f4s(INFINITY);

    // ---- main sweep: one barrier per row; all LDS reads see >=1-barrier-old data ----
    #pragma unroll 2
    for (int L = y0; L < y0 + CH + 7; ++L) {
        // Early LDS edge reads (all written before the previous barrier).
        float4 eL = (wv > 0)      ? s_iR[(L - 3) & 3][wv - 1] : f4s(0.f);
        float4 eR = (wv < NW - 1) ? s_iL[(L - 3) & 3][wv + 1] : f4s(0.f);
        float glE = (wv > 0)      ? s_gR[(L - 1) & 1][wv - 1] : -INFINITY;
        float grE = (wv < NW - 1) ? s_gL[(L - 1) & 1][wv + 1] : -INFINITY;
        float vlE = (wv > 0)      ? s_vR[(L - 1) & 1][wv - 1] : INFINITY;
        float vrE = (wv < NW - 1) ? s_vL[(L - 1) & 1][wv + 1] : INFINITY;

        // consume prefetched row L; shift ring; prefetch row L+1
        float4 v = vpref;
        im6 = im5; im5 = im4; im4 = im3; im3 = im2; im2 = im1; im1 = im0; im0 = v;
        int Lp = L + 1;
        vpref = f4s(0.f);
        if (Lp < Hd) vpref = *(const float4*)(ip + (size_t)Lp * Wd);

        // ---- gradient row L-3 (registers + shfl; img zero-pad semantics) ----
        float4 ce = im3;
        float4 lf = shflup1(ce);
        if (lane == 0)  lf = eL;
        float4 rt = shfldn1(ce);
        if (lane == 63) rt = eR;

        float4 gv;
        {
            const float K = 255.75f;  // 1023/4 exact
            float gx0 = masked_grad1(ce.y - lf.w, ce.z - lf.z, ce.w - lf.y);
            float gx1 = masked_grad1(ce.z - ce.x, ce.w - lf.w, rt.x - lf.z);
            float gx2 = masked_grad1(ce.w - ce.y, rt.x - ce.x, rt.y - lf.w);
            float gx3 = masked_grad1(rt.x - ce.z, rt.y - ce.y, rt.z - ce.x);
            float gy0 = masked_grad1(im2.x - im4.x, im1.x - im5.x, im0.x - im6.x);
            float gy1 = masked_grad1(im2.y - im4.y, im1.y - im5.y, im0.y - im6.y);
            float gy2 = masked_grad1(im2.z - im4.z, im1.z - im5.z, im0.z - im6.z);
            float gy3 = masked_grad1(im2.w - im4.w, im1.w - im5.w, im0.w - im6.w);
            gv.x = fmaxf(fabsf(gx0), fabsf(gy0)) * K;
            gv.y = fmaxf(fabsf(gx1), fabsf(gy1)) * K;
            gv.z = fmaxf(fabsf(gx2), fabsf(gy2)) * K;
            gv.w = fmaxf(fabsf(gx3), fabsf(gy3)) * K;
        }

        // ---- hmax row L-4 (gprev = grad row L-4, edges 1 barrier old) ----
        float gl = __shfl_up(gprev.w, 1, 64);
        if (lane == 0)  gl = glE;
        float gr = __shfl_down(gprev.x, 1, 64);
        if (lane == 63) gr = grE;
        float4 hm;
        hm.x = fmaxf(fmaxf(gl, gprev.x), gprev.y);
        hm.y = fmaxf(fmaxf(gprev.x, gprev.y), gprev.z);
        hm.z = fmaxf(fmaxf(gprev.y, gprev.z), gprev.w);
        hm.w = fmaxf(fmaxf(gprev.z, gprev.w), gr);
        if ((unsigned)(L - 4) >= (unsigned)Hd) hm = f4s(-INFINITY);

        // ---- vmax row L-5 (vertical max of hmax ring) ----
        float4 vm;
        vm.x = fmaxf(fmaxf(h0.x, h1.x), hm.x);
        vm.y = fmaxf(fmaxf(h0.y, h1.y), hm.y);
        vm.z = fmaxf(fmaxf(h0.z, h1.z), hm.z);
        vm.w = fmaxf(fmaxf(h0.w, h1.w), hm.w);
        if ((unsigned)(L - 5) >= (unsigned)Hd) vm = f4s(INFINITY);

        // ---- hmin row L-6 (vmprev = vmax row L-6, edges 1 barrier old) ----
        float vl = __shfl_up(vmprev.w, 1, 64);
        if (lane == 0)  vl = vlE;
        float vr = __shfl_down(vmprev.x, 1, 64);
        if (lane == 63) vr = vrE;
        float4 hn;
        hn.x = fminf(fminf(vl, vmprev.x), vmprev.y);
        hn.y = fminf(fminf(vmprev.x, vmprev.y), vmprev.z);
        hn.z = fminf(fminf(vmprev.y, vmprev.z), vmprev.w);
        hn.w = fminf(fminf(vmprev.z, vmprev.w), vr);

        // ---- output row L-7 (vertical min of hmin ring) ----
        int O = L - 7;
        if (O >= y0) {   // O <= y0+CH-1 guaranteed by loop bound
            float4 o;
            o.x = fminf(fminf(n0.x, n1.x), hn.x);
            o.y = fminf(fminf(n0.y, n1.y), hn.y);
            o.z = fminf(fminf(n0.z, n1.z), hn.z);
            o.w = fminf(fminf(n0.w, n1.w), hn.w);
            *(float4*)(op + (size_t)O * Wd) = o;
        }

        // ---- batched edge publishes (pre-barrier; consumed next iters) ----
        if (lane == 0) {
            s_iL[L & 3][wv] = v;
            s_gL[L & 1][wv] = gv.x;
            s_vL[L & 1][wv] = vm.x;
        }
        if (lane == 63) {
            s_iR[L & 3][wv] = v;
            s_gR[L & 1][wv] = gv.w;
            s_vR[L & 1][wv] = vm.w;
        }

        gprev = gv; h0 = h1; h1 = hm; vmprev = vm; n0 = n1; n1 = hn;
        __syncthreads();
    }
}

extern "C" void kernel_launch(void* const* d_in, const int* in_sizes, int n_in,
                              void* d_out, int out_size, void* d_ws, size_t ws_size,
                              hipStream_t stream) {
    const float* img = (const float*)d_in[0];
    float* out = (float*)d_out;
    dim3 grid(Hd / CH, BC);   // 32 x 24 = 768 blocks
    dim3 block(NT);
    gradmap_shfl_kernel<<<grid, block, 0, stream>>>(img, out);
}

// Round 4
// 110.490 us; speedup vs baseline: 1.2854x; 1.2854x over previous
//
#include <hip/hip_runtime.h>
#include <math.h>

// img (8, 3, 1024, 2048) fp32 -> same-shape fp32 output.
#define Wd 2048
#define Hd 1024
#define BC 24
#define CH 32          // output rows per block
#define NT 512         // 8 waves; lane owns 4 consecutive cols
#define NW 8
#define SROW (Wd + 8)  // img LDS row: col c stored at index c+4 (halo +-4)

__device__ __forceinline__ float masked_grad1(float g1, float g2, float g3) {
    const float HALF_T     = (float)(0.5 / 1023.0);
    const float GRD_BOTTOM = (float)(1.0 / 1023.0);
    const float GRD_UP     = (float)(4.0 / 1023.0);
    const float THIRD      = (float)(1.0 / 3.0);
    float m = (g1 + g2 + g3) * THIRD;
    float g = (g1 < m - HALF_T || g1 > m + HALF_T) ? 0.0f : g1;
    float ag = fabsf(g);
    if (ag < GRD_BOTTOM || ag > GRD_UP) g = 0.0f;
    return g;
}

__device__ __forceinline__ float4 f4s(float v) { return make_float4(v, v, v, v); }

__global__ __launch_bounds__(NT) void gradmap_hybrid_kernel(
        const float* __restrict__ img, float* __restrict__ out) {
    const int plane = blockIdx.y;
    const int y0 = blockIdx.x * CH;
    const int tid = threadIdx.x;
    const int lane = tid & 63;
    const int wv = tid >> 6;
    const int c0 = tid << 2;
    const float* __restrict__ ip = img + (size_t)plane * Hd * Wd + c0;
    float* __restrict__ op = out + (size_t)plane * Hd * Wd + c0;

    // img ring in LDS (wide x-halo via conflict-free b128 reads),
    // grad/vmax wave-edge scalars via parity-double-buffered tiny LDS.
    __shared__ float s_img[4][SROW];
    __shared__ float s_gL[2][NW], s_gR[2][NW];   // grad row edges
    __shared__ float s_vL[2][NW], s_vR[2][NW];   // vmax row edges

    // constant zero halo columns (written once, in-loop writes never touch)
    if (tid < 32) {
        int r = tid >> 3, j = tid & 7;
        int col = (j < 4) ? j : (Wd + j);  // 0..3 and Wd+4..Wd+7
        s_img[r][col] = 0.0f;
    }

    // img register ring: im0 = newest row L ... im6 = row L-6 (own 4 cols)
    float4 im0 = f4s(0.f), im1 = f4s(0.f), im2 = f4s(0.f), im3 = f4s(0.f),
           im4 = f4s(0.f), im5 = f4s(0.f), im6 = f4s(0.f);

    // ---- prime: rows y0-6 .. y0-1 ----
    #pragma unroll
    for (int r = 0; r < 6; ++r) {
        int row = y0 - 6 + r;
        float4 v = f4s(0.f);
        if (row >= 0) v = *(const float4*)(ip + (size_t)row * Wd);
        im6 = im5; im5 = im4; im4 = im3; im3 = im2; im2 = im1; im1 = im0; im0 = v;
        *(float4*)&s_img[row & 3][c0 + 4] = v;
    }
    float4 vpref = *(const float4*)(ip + (size_t)y0 * Wd);  // y0 < Hd always
    __syncthreads();

    float4 gprev  = f4s(0.f);
    float4 h0 = f4s(-INFINITY), h1 = f4s(-INFINITY);
    float4 vmprev = f4s(INFINITY);
    float4 n0 = f4s(INFINITY), n1 = f4s(INFINITY);

    // ---- main sweep: one barrier per row; skewed pipeline ----
    #pragma unroll 4
    for (int L = y0; L < y0 + CH + 7; ++L) {
        // wave-edge scalars published last iteration (>=1 barrier old)
        float glE = (wv > 0)      ? s_gR[(L - 1) & 1][wv - 1] : -INFINITY;
        float grE = (wv < NW - 1) ? s_gL[(L - 1) & 1][wv + 1] : -INFINITY;
        float vlE = (wv > 0)      ? s_vR[(L - 1) & 1][wv - 1] : INFINITY;
        float vrE = (wv < NW - 1) ? s_vL[(L - 1) & 1][wv + 1] : INFINITY;

        // consume prefetched row L; shift ring; write LDS; prefetch row L+1
        float4 v = vpref;
        im6 = im5; im5 = im4; im4 = im3; im3 = im2; im2 = im1; im1 = im0; im0 = v;
        *(float4*)&s_img[L & 3][c0 + 4] = v;
        vpref = f4s(0.f);
        if (L + 1 < Hd) vpref = *(const float4*)(ip + (size_t)(L + 1) * Wd);

        // ---- gradient row L-3: x-halo via LDS (written 3 barriers ago) ----
        const float* sr = s_img[(L - 3) & 3];
        float4 lf = *(const float4*)&sr[c0];       // cols c0-4..c0-1
        float4 rt = *(const float4*)&sr[c0 + 8];   // cols c0+4..c0+7
        float4 ce = im3;

        float4 gv;
        {
            const float K = 255.75f;  // 1023/4 exact
            float gx0 = masked_grad1(ce.y - lf.w, ce.z - lf.z, ce.w - lf.y);
            float gx1 = masked_grad1(ce.z - ce.x, ce.w - lf.w, rt.x - lf.z);
            float gx2 = masked_grad1(ce.w - ce.y, rt.x - ce.x, rt.y - lf.w);
            float gx3 = masked_grad1(rt.x - ce.z, rt.y - ce.y, rt.z - ce.x);
            float gy0 = masked_grad1(im2.x - im4.x, im1.x - im5.x, im0.x - im6.x);
            float gy1 = masked_grad1(im2.y - im4.y, im1.y - im5.y, im0.y - im6.y);
            float gy2 = masked_grad1(im2.z - im4.z, im1.z - im5.z, im0.z - im6.z);
            float gy3 = masked_grad1(im2.w - im4.w, im1.w - im5.w, im0.w - im6.w);
            gv.x = fmaxf(fabsf(gx0), fabsf(gy0)) * K;
            gv.y = fmaxf(fabsf(gx1), fabsf(gy1)) * K;
            gv.z = fmaxf(fabsf(gx2), fabsf(gy2)) * K;
            gv.w = fmaxf(fabsf(gx3), fabsf(gy3)) * K;
        }

        // ---- hmax row L-4 (gprev = grad row L-4; edges 1 barrier old) ----
        float gl = __shfl_up(gprev.w, 1, 64);
        if (lane == 0)  gl = glE;
        float gr = __shfl_down(gprev.x, 1, 64);
        if (lane == 63) gr = grE;
        float4 hm;
        hm.x = fmaxf(fmaxf(gl, gprev.x), gprev.y);
        hm.y = fmaxf(fmaxf(gprev.x, gprev.y), gprev.z);
        hm.z = fmaxf(fmaxf(gprev.y, gprev.z), gprev.w);
        hm.w = fmaxf(fmaxf(gprev.z, gprev.w), gr);
        if ((unsigned)(L - 4) >= (unsigned)Hd) hm = f4s(-INFINITY);

        // ---- vmax row L-5 ----
        float4 vm;
        vm.x = fmaxf(fmaxf(h0.x, h1.x), hm.x);
        vm.y = fmaxf(fmaxf(h0.y, h1.y), hm.y);
        vm.z = fmaxf(fmaxf(h0.z, h1.z), hm.z);
        vm.w = fmaxf(fmaxf(h0.w, h1.w), hm.w);
        if ((unsigned)(L - 5) >= (unsigned)Hd) vm = f4s(INFINITY);

        // ---- hmin row L-6 (vmprev = vmax row L-6; edges 1 barrier old) ----
        float vl = __shfl_up(vmprev.w, 1, 64);
        if (lane == 0)  vl = vlE;
        float vr = __shfl_down(vmprev.x, 1, 64);
        if (lane == 63) vr = vrE;
        float4 hn;
        hn.x = fminf(fminf(vl, vmprev.x), vmprev.y);
        hn.y = fminf(fminf(vmprev.x, vmprev.y), vmprev.z);
        hn.z = fminf(fminf(vmprev.y, vmprev.z), vmprev.w);
        hn.w = fminf(fminf(vmprev.z, vmprev.w), vr);

        // ---- output row L-7 ----
        int O = L - 7;
        if (O >= y0) {   // O <= y0+CH-1 by loop bound
            float4 o;
            o.x = fminf(fminf(n0.x, n1.x), hn.x);
            o.y = fminf(fminf(n0.y, n1.y), hn.y);
            o.z = fminf(fminf(n0.z, n1.z), hn.z);
            o.w = fminf(fminf(n0.w, n1.w), hn.w);
            *(float4*)(op + (size_t)O * Wd) = o;
        }

        // ---- edge publishes (pre-barrier; consumed next iteration) ----
        if (lane == 0) {
            s_gL[L & 1][wv] = gv.x;
            s_vL[L & 1][wv] = vm.x;
        }
        if (lane == 63) {
            s_gR[L & 1][wv] = gv.w;
            s_vR[L & 1][wv] = vm.w;
        }

        gprev = gv; h0 = h1; h1 = hm; vmprev = vm; n0 = n1; n1 = hn;
        __syncthreads();
    }
}

extern "C" void kernel_launch(void* const* d_in, const int* in_sizes, int n_in,
                              void* d_out, int out_size, void* d_ws, size_t ws_size,
                              hipStream_t stream) {
    const float* img = (const float*)d_in[0];
    float* out = (float*)d_out;
    dim3 grid(Hd / CH, BC);   // 32 x 24 = 768 blocks
    dim3 block(NT);
    gradmap_hybrid_kernel<<<grid, block, 0, stream>>>(img, out);
}

// Round 5
// 101.794 us; speedup vs baseline: 1.3952x; 1.0854x over previous
//
#include <hip/hip_runtime.h>
#include <math.h>

// img (8, 3, 1024, 2048) fp32 -> same-shape fp32 output.
#define Wd 2048
#define Hd 1024
#define BC 24
#define CH 32          // output rows per block (y0 = 32*chunk, so y0 % 8 == 0)
#define NT 512         // 8 waves; lane owns 4 consecutive cols
#define NW 8
#define SROW (Wd + 8)  // img LDS row: col c at index c+4 (zero halo +-4)

__device__ __forceinline__ float4 f4s(float v) { return make_float4(v, v, v, v); }

// Exact-equivalent rewrite of the reference masking (4 compares, 1 select).
// keep <=> !(g1 < m-HALF) && !(g1 > m+HALF) && !(|g1| < BOT) && !(|g1| > UP)
// (when the first test fails, both forms give 0; |g| == |g1| when kept)
__device__ __forceinline__ float masked_grad1(float g1, float g2, float g3) {
    const float HALF_T     = (float)(0.5 / 1023.0);
    const float GRD_BOTTOM = (float)(1.0 / 1023.0);
    const float GRD_UP     = (float)(4.0 / 1023.0);
    const float THIRD      = (float)(1.0 / 3.0);
    float m  = (g1 + g2 + g3) * THIRD;
    float lo = m - HALF_T;
    float hi = m + HALF_T;
    float a  = fabsf(g1);
    bool keep = (g1 >= lo) & (g1 <= hi) & (a >= GRD_BOTTOM) & (a <= GRD_UP);
    return keep ? g1 : 0.0f;
}

struct State {
    float4 im[8];   // img rows: row r lives in im[r & 7]
    float4 vp[2];   // global prefetch, row r in vp[r & 1] (2 rows in flight)
    float4 g[2];    // grad row produced by body with parity p -> g[p]
    float4 hr[2];   // hmax ring (body-parity indexed)
    float4 vr[2];   // vmax ring
    float4 nr[2];   // hmin ring
};

// LDS-visibility barrier WITHOUT the vmcnt(0) drain __syncthreads would add:
// global prefetch loads stay in flight across rows.
__device__ __forceinline__ void row_barrier() {
    asm volatile("s_waitcnt lgkmcnt(0)" ::: "memory");
    __builtin_amdgcn_s_barrier();
    asm volatile("" ::: "memory");
}

// One pipeline row. LM8 == L & 7 (compile-time; y0 % 8 == 0 everywhere).
// Dataflow identical to the verified round-4 kernel:
//   load row L+2 (2-deep prefetch), grad row L-3, hmax row L-4,
//   vmax row L-5, hmin row L-6, out row L-7.
template<int LM8, bool EDGE, bool STORE>
__device__ __forceinline__ void row_body(
        int L, State& S, const float* __restrict__ ip, float* __restrict__ op,
        int lane, int wv, int c0,
        float (*s_img)[SROW], float (*s_gL)[NW], float (*s_gR)[NW],
        float (*s_vL)[NW], float (*s_vR)[NW]) {
    constexpr int IW = LM8 & 7;        // im slot for row L
    constexpr int SW = LM8 & 3;        // s_img write slot (row L)
    constexpr int SR = (LM8 + 1) & 3;  // s_img read slot (row L-3)
    constexpr int PW = LM8 & 1;        // this body's parity
    constexpr int PR = (LM8 + 1) & 1;  // previous body's parity

    // cross-wave edge scalars published by the previous body (1 barrier old)
    float glE = (wv > 0)      ? s_gR[PR][wv - 1] : -INFINITY;
    float grE = (wv < NW - 1) ? s_gL[PR][wv + 1] : -INFINITY;
    float vlE = (wv > 0)      ? s_vR[PR][wv - 1] : INFINITY;
    float vrE = (wv < NW - 1) ? s_vL[PR][wv + 1] : INFINITY;

    // consume prefetched row L; publish to LDS ring; issue row L+2
    float4 v = S.vp[PW];
    S.im[IW] = v;
    *(float4*)&s_img[SW][c0 + 4] = v;
    {
        int Ln = L + 2;
        float4 nv = f4s(0.f);
        if (!EDGE || (unsigned)Ln < (unsigned)Hd)
            nv = *(const float4*)(ip + (size_t)Ln * Wd + c0);
        S.vp[PW] = nv;
    }

    // ---- gradient row L-3 ----
    const float* sr = s_img[SR];
    float4 lf = *(const float4*)&sr[c0];      // cols c0-4..c0-1 (zero halo)
    float4 rt = *(const float4*)&sr[c0 + 8];  // cols c0+4..c0+7
    float4 ce = S.im[(LM8 + 5) & 7];          // row L-3
    float4 rA = S.im[(LM8 + 6) & 7];          // row L-2
    float4 rB = S.im[(LM8 + 4) & 7];          // row L-4
    float4 rC = S.im[(LM8 + 7) & 7];          // row L-1
    float4 rD = S.im[(LM8 + 3) & 7];          // row L-5
    float4 rE = v;                            // row L
    float4 rF = S.im[(LM8 + 2) & 7];          // row L-6

    float4 gv;
    {
        const float K = 255.75f;  // 1023/4 exact
        float gx0 = masked_grad1(ce.y - lf.w, ce.z - lf.z, ce.w - lf.y);
        float gx1 = masked_grad1(ce.z - ce.x, ce.w - lf.w, rt.x - lf.z);
        float gx2 = masked_grad1(ce.w - ce.y, rt.x - ce.x, rt.y - lf.w);
        float gx3 = masked_grad1(rt.x - ce.z, rt.y - ce.y, rt.z - ce.x);
        float gy0 = masked_grad1(rA.x - rB.x, rC.x - rD.x, rE.x - rF.x);
        float gy1 = masked_grad1(rA.y - rB.y, rC.y - rD.y, rE.y - rF.y);
        float gy2 = masked_grad1(rA.z - rB.z, rC.z - rD.z, rE.z - rF.z);
        float gy3 = masked_grad1(rA.w - rB.w, rC.w - rD.w, rE.w - rF.w);
        gv.x = fmaxf(fabsf(gx0), fabsf(gy0)) * K;
        gv.y = fmaxf(fabsf(gx1), fabsf(gy1)) * K;
        gv.z = fmaxf(fabsf(gx2), fabsf(gy2)) * K;
        gv.w = fmaxf(fabsf(gx3), fabsf(gy3)) * K;
    }

    // ---- hmax row L-4 (g[PR] = grad row L-4; its edges are 1 barrier old) ----
    float4 gp = S.g[PR];
    float gl = __shfl_up(gp.w, 1, 64);
    if (lane == 0)  gl = glE;
    float gr = __shfl_down(gp.x, 1, 64);
    if (lane == 63) gr = grE;
    float4 hm;
    hm.x = fmaxf(fmaxf(gl,   gp.x), gp.y);
    hm.y = fmaxf(fmaxf(gp.x, gp.y), gp.z);
    hm.z = fmaxf(fmaxf(gp.y, gp.z), gp.w);
    hm.w = fmaxf(fmaxf(gp.z, gp.w), gr);
    if (EDGE) { if ((unsigned)(L - 4) >= (unsigned)Hd) hm = f4s(-INFINITY); }

    // ---- vmax row L-5 = max(hmax L-6, L-5, L-4) ----
    float4 h6 = S.hr[PW];  // row L-6 (written 2 bodies ago)
    float4 h5 = S.hr[PR];  // row L-5
    float4 vm;
    vm.x = fmaxf(fmaxf(h6.x, h5.x), hm.x);
    vm.y = fmaxf(fmaxf(h6.y, h5.y), hm.y);
    vm.z = fmaxf(fmaxf(h6.z, h5.z), hm.z);
    vm.w = fmaxf(fmaxf(h6.w, h5.w), hm.w);
    if (EDGE) { if ((unsigned)(L - 5) >= (unsigned)Hd) vm = f4s(INFINITY); }
    S.hr[PW] = hm;

    // ---- hmin row L-6 (vr[PR] = vmax row L-6; edges 1 barrier old) ----
    float4 vq = S.vr[PR];
    float vl = __shfl_up(vq.w, 1, 64);
    if (lane == 0)  vl = vlE;
    float vr_ = __shfl_down(vq.x, 1, 64);
    if (lane == 63) vr_ = vrE;
    float4 hn;
    hn.x = fminf(fminf(vl,   vq.x), vq.y);
    hn.y = fminf(fminf(vq.x, vq.y), vq.z);
    hn.z = fminf(fminf(vq.y, vq.z), vq.w);
    hn.w = fminf(fminf(vq.z, vq.w), vr_);
    S.vr[PW] = vm;

    // ---- out row L-7 = min(hmin L-8, L-7, L-6) ----
    if (STORE) {
        float4 n8 = S.nr[PW];  // row L-8
        float4 n7 = S.nr[PR];  // row L-7
        float4 o;
        o.x = fminf(fminf(n8.x, n7.x), hn.x);
        o.y = fminf(fminf(n8.y, n7.y), hn.y);
        o.z = fminf(fminf(n8.z, n7.z), hn.z);
        o.w = fminf(fminf(n8.w, n7.w), hn.w);
        *(float4*)(op + (size_t)(L - 7) * Wd + c0) = o;
    }
    S.nr[PW] = hn;
    S.g[PW]  = gv;

    // ---- edge publishes (consumed by the next body) ----
    if (lane == 0)  { s_gL[PW][wv] = gv.x; s_vL[PW][wv] = vm.x; }
    if (lane == 63) { s_gR[PW][wv] = gv.w; s_vR[PW][wv] = vm.w; }

    row_barrier();
}

template<bool EDGE>
__device__ __forceinline__ void run_sweep(
        const float* __restrict__ ip, float* __restrict__ op, int y0,
        int tid, int lane, int wv, int c0,
        float (*s_img)[SROW], float (*s_gL)[NW], float (*s_gR)[NW],
        float (*s_vL)[NW], float (*s_vR)[NW]) {
    // constant zero halo columns (in-loop writes never touch them)
    if (tid < 32) {
        int r = tid >> 3, j = tid & 7;
        int col = (j < 4) ? j : (Wd + j);
        s_img[r][col] = 0.0f;
    }

    State S;
    #pragma unroll
    for (int i = 0; i < 8; ++i) S.im[i] = f4s(0.f);
    S.g[0] = S.g[1] = f4s(0.f);
    S.hr[0] = S.hr[1] = f4s(-INFINITY);
    S.vr[0] = S.vr[1] = f4s(INFINITY);
    S.nr[0] = S.nr[1] = f4s(INFINITY);

    // ---- prime: rows y0-6 .. y0-1 ----
    #pragma unroll
    for (int r = 0; r < 6; ++r) {
        int row = y0 - 6 + r;
        float4 v = f4s(0.f);
        if (!EDGE || row >= 0) v = *(const float4*)(ip + (size_t)row * Wd + c0);
        S.im[(r + 2) & 7] = v;                         // (y0-6+r)&7, y0%8==0
        *(float4*)&s_img[(r + 2) & 3][c0 + 4] = v;
    }
    S.vp[0] = *(const float4*)(ip + (size_t)y0 * Wd + c0);        // row y0
    S.vp[1] = *(const float4*)(ip + (size_t)(y0 + 1) * Wd + c0);  // row y0+1
    __syncthreads();

    // ---- warm-up: 7 bodies, no store (fills rings/edges) ----
    row_body<0, EDGE, false>(y0 + 0, S, ip, op, lane, wv, c0, s_img, s_gL, s_gR, s_vL, s_vR);
    row_body<1, EDGE, false>(y0 + 1, S, ip, op, lane, wv, c0, s_img, s_gL, s_gR, s_vL, s_vR);
    row_body<2, EDGE, false>(y0 + 2, S, ip, op, lane, wv, c0, s_img, s_gL, s_gR, s_vL, s_vR);
    row_body<3, EDGE, false>(y0 + 3, S, ip, op, lane, wv, c0, s_img, s_gL, s_gR, s_vL, s_vR);
    row_body<4, EDGE, false>(y0 + 4, S, ip, op, lane, wv, c0, s_img, s_gL, s_gR, s_vL, s_vR);
    row_body<5, EDGE, false>(y0 + 5, S, ip, op, lane, wv, c0, s_img, s_gL, s_gR, s_vL, s_vR);
    row_body<6, EDGE, false>(y0 + 6, S, ip, op, lane, wv, c0, s_img, s_gL, s_gR, s_vL, s_vR);

    // ---- steady: 32 bodies, always store; all ring slots compile-time ----
    #pragma unroll 1
    for (int jj = 0; jj < CH; jj += 8) {
        const int Lb = y0 + 7 + jj;   // Lb % 8 == 7
        row_body<7, EDGE, true>(Lb + 0, S, ip, op, lane, wv, c0, s_img, s_gL, s_gR, s_vL, s_vR);
        row_body<0, EDGE, true>(Lb + 1, S, ip, op, lane, wv, c0, s_img, s_gL, s_gR, s_vL, s_vR);
        row_body<1, EDGE, true>(Lb + 2, S, ip, op, lane, wv, c0, s_img, s_gL, s_gR, s_vL, s_vR);
        row_body<2, EDGE, true>(Lb + 3, S, ip, op, lane, wv, c0, s_img, s_gL, s_gR, s_vL, s_vR);
        row_body<3, EDGE, true>(Lb + 4, S, ip, op, lane, wv, c0, s_img, s_gL, s_gR, s_vL, s_vR);
        row_body<4, EDGE, true>(Lb + 5, S, ip, op, lane, wv, c0, s_img, s_gL, s_gR, s_vL, s_vR);
        row_body<5, EDGE, true>(Lb + 6, S, ip, op, lane, wv, c0, s_img, s_gL, s_gR, s_vL, s_vR);
        row_body<6, EDGE, true>(Lb + 7, S, ip, op, lane, wv, c0, s_img, s_gL, s_gR, s_vL, s_vR);
    }
}

__global__ __launch_bounds__(NT) void gradmap_pipe_kernel(
        const float* __restrict__ img, float* __restrict__ out) {
    const int plane = blockIdx.y;
    const int y0 = blockIdx.x * CH;
    const int tid = threadIdx.x;
    const int lane = tid & 63;
    const int wv = tid >> 6;
    const int c0 = tid << 2;
    const float* ip = img + (size_t)plane * Hd * Wd;
    float* op = out + (size_t)plane * Hd * Wd;

    __shared__ float s_img[4][SROW];
    __shared__ float s_gL[2][NW], s_gR[2][NW];
    __shared__ float s_vL[2][NW], s_vR[2][NW];

    // only the first/last row-chunks ever touch image top/bottom padding
    if (blockIdx.x == 0 || blockIdx.x == gridDim.x - 1)
        run_sweep<true >(ip, op, y0, tid, lane, wv, c0, s_img, s_gL, s_gR, s_vL, s_vR);
    else
        run_sweep<false>(ip, op, y0, tid, lane, wv, c0, s_img, s_gL, s_gR, s_vL, s_vR);
}

extern "C" void kernel_launch(void* const* d_in, const int* in_sizes, int n_in,
                              void* d_out, int out_size, void* d_ws, size_t ws_size,
                              hipStream_t stream) {
    const float* img = (const float*)d_in[0];
    float* out = (float*)d_out;
    dim3 grid(Hd / CH, BC);   // 32 x 24 = 768 blocks = 3/CU, balanced
    dim3 block(NT);
    gradmap_pipe_kernel<<<grid, block, 0, stream>>>(img, out);
}